// Round 11
// baseline (573.618 us; speedup 1.0000x reference)
//
#include <hip/hip_runtime.h>

typedef float f4 __attribute__((ext_vector_type(4)));

constexpr int N_  = 4;
constexpr int C_  = 320;
constexpr int H_  = 80;
constexpr int W_  = 160;
constexpr int G_  = 40;
constexpr int CPG = 8;                       // channels per group
constexpr int D_  = 48;                      // max disparity
constexpr int HW  = H_ * W_;                 // channel stride in floats
constexpr int TILES = (W_ / 4) * (D_ / 4);   // 480 4w x 4d tiles per row

__global__ __launch_bounds__(256, 8) void gw_cost_kernel(const float* __restrict__ Lg,
                                                         const float* __restrict__ Rg,
                                                         float* __restrict__ out) {
    // NO LDS, NO barrier: compute straight from global through L1/L2.
    // Block working set = 10 KB (L1-sized); each R f4 re-read by <=12 wave-insts.
    const int tid = threadIdx.x;
    const int blk = blockIdx.x;               // ((n*G + g)*H + h)

    const int h = blk % H_;
    const int g = (blk / H_) % G_;
    const int n = blk / (H_ * G_);

    const float* Lrow = Lg + (size_t)(n * C_ + g * CPG) * HW + (size_t)h * W_;
    const float* Rrow = Rg + (size_t)(n * C_ + g * CPG) * HW + (size_t)h * W_;
    float* orow = out + (size_t)blk * (W_ * D_);

    auto do_tile = [&](int t) {
        const int tw = t / 12;
        const int td = t % 12;
        const int w0 = tw * 4;
        const int d0 = td * 4;
        const int s  = w0 - d0;               // window base: rr[idx] = R[s-4+idx]

        f4 a0 = (f4)(0.f), a1 = (f4)(0.f), a2 = (f4)(0.f), a3 = (f4)(0.f);

        if (s >= 0) {                         // s <= -4 lanes: tile is all zeros
            #pragma unroll
            for (int c = 0; c < CPG; ++c) {
                const float* Lc = Lrow + (size_t)c * HW;
                const float* Rc = Rrow + (size_t)c * HW;
                const f4 lv = *(const f4*)(Lc + w0);
                const f4 rb = *(const f4*)(Rc + s);        // R[s..s+3], s>=0
                f4 ra = (f4)(0.f);
                if (s >= 4) ra = *(const f4*)(Rc + (s - 4)); // R[s-4..s-1]; diag keeps 0
                float rr[8];
                #pragma unroll
                for (int k = 0; k < 4; ++k) { rr[k] = ra[k]; rr[4 + k] = rb[k]; }
                // out(w0+i, d0+j) += L[w0+i] * R[s + i - j] -> rr[4 + i - j], idx 1..7
                #pragma unroll
                for (int j = 0; j < 4; ++j) {
                    a0[j] += lv[0] * rr[4 + 0 - j];
                    a1[j] += lv[1] * rr[4 + 1 - j];
                    a2[j] += lv[2] * rr[4 + 2 - j];
                    a3[j] += lv[3] * rr[4 + 3 - j];
                }
            }
        }

        float* op = orow + (size_t)w0 * D_ + d0;   // zero-tiles still store zeros
        *(f4*)(op + 0 * D_) = a0 * 0.125f;
        *(f4*)(op + 1 * D_) = a1 * 0.125f;
        *(f4*)(op + 2 * D_) = a2 * 0.125f;
        *(f4*)(op + 3 * D_) = a3 * 0.125f;
    };

    do_tile(tid);                              // tiles 0..255 (mixed classes)
    if (tid + 256 < TILES) do_tile(tid + 256); // tiles 256..479 (all full, no divergence)
}

extern "C" void kernel_launch(void* const* d_in, const int* in_sizes, int n_in,
                              void* d_out, int out_size, void* d_ws, size_t ws_size,
                              hipStream_t stream) {
    const float* Lg = (const float*)d_in[0];
    const float* Rg = (const float*)d_in[1];
    float* out = (float*)d_out;

    const int nblocks = N_ * G_ * H_;   // 12800 blocks, one per (n, g, h)
    gw_cost_kernel<<<dim3(nblocks), dim3(256), 0, stream>>>(Lg, Rg, out);
}

// Round 12
// 107.316 us; speedup vs baseline: 5.3451x; 5.3451x over previous
//
#include <hip/hip_runtime.h>

typedef float f4 __attribute__((ext_vector_type(4)));

constexpr int N_  = 4;
constexpr int C_  = 320;
constexpr int H_  = 80;
constexpr int W_  = 160;
constexpr int G_  = 40;
constexpr int CPG = 8;                        // channels per group
constexpr int D_  = 48;                       // max disparity
constexpr int PAD = 48;                       // zero pad in front of each R row
constexpr int RW  = PAD + W_;                 // 208 floats per R row slot
constexpr int HW  = H_ * W_;                  // channel stride in floats
constexpr int H2  = 2;                        // h-rows per block
constexpr int TPB = H2 * (W_ / 4) * (D_ / 4); // 960 4w x 4d tiles per block

__global__ __launch_bounds__(512, 8) void gw_cost_kernel(const float* __restrict__ Lg,
                                                         const float* __restrict__ Rg,
                                                         float* __restrict__ out) {
    // Ls: channel c at floats [c*320, c*320+320) = rows h0,h0+1 contiguous (as in global)
    // Rs: channel c, row hh at [c*416 + hh*208, +208); first 48 floats = zero pad
    __shared__ float Ls[CPG * H2 * W_];   // 10240 B
    __shared__ float Rs[CPG * H2 * RW];   // 13312 B   (23.5 KB -> 4 blocks/CU, 32 waves)

    const int tid  = threadIdx.x;
    const int wid  = tid >> 6;            // 8 waves
    const int lane = tid & 63;
    const int blk  = blockIdx.x;          // ((n*G + g)*(H/2) + h2)

    const int h2 = blk % (H_ / H2);
    const int g  = (blk / (H_ / H2)) % G_;
    const int n  = blk / ((H_ / H2) * G_);
    const int h0 = h2 * H2;

    const size_t base2 = (size_t)(n * C_ + g * CPG) * HW + (size_t)h0 * W_;

    // zero the R pads: 192 f4, one ds_write for tid<192
    if (tid < CPG * H2 * (PAD / 4)) {
        const int c = tid / 24, rem = tid % 24;
        const int hh = rem / 12, p4 = rem % 12;
        *(f4*)&Rs[c * (H2 * RW) + hh * RW + p4 * 4] = (f4)(0.0f);
    }

    // ---- L staging: 10 full-64-lane DMA instructions (1024 B each). ----
    // f4 #idx (idx = k*64+lane): c = idx/80, q = idx%80 spans the channel's
    // 2 contiguous rows in global; LDS dest linear (uniform base + lane*16).
    {
        auto issueL = [&](int k) {
            const int idx = k * 64 + lane;
            const int c = idx / 80, q = idx % 80;
            const float* s = Lg + base2 + (size_t)c * HW + q * 4;
            __builtin_amdgcn_global_load_lds(
                (const __attribute__((address_space(1))) void*)s,
                (__attribute__((address_space(3))) void*)&Ls[k * 256], 16, 0, 0);
        };
        issueL(wid);
        if (wid < 2) issueL(8 + wid);
    }
    // ---- R staging: wave w DMAs channel w's two rows (40 lanes x 16 B each). ----
    if (lane < 40) {
        #pragma unroll
        for (int hh = 0; hh < H2; ++hh) {
            const float* s = Rg + base2 + (size_t)wid * HW + hh * W_ + lane * 4;
            __builtin_amdgcn_global_load_lds(
                (const __attribute__((address_space(1))) void*)s,
                (__attribute__((address_space(3))) void*)&Rs[wid * (H2 * RW) + hh * RW + PAD],
                16, 0, 0);
        }
    }
    __syncthreads();

    // ---- compute: R6's proven 4w x 4d core, two rows' tiles ----
    for (int t = tid; t < TPB; t += 512) {
        const int hh  = t / 480;
        const int rem = t % 480;
        const int tw = rem / 12;
        const int td = rem % 12;
        const int w0 = tw * 4;
        const int d0 = td * 4;
        const int r0 = w0 - d0 + PAD;   // [4, 204]; reads r0-4 .. r0+3 within [0, 207]

        f4 a0 = (f4)(0.f), a1 = (f4)(0.f), a2 = (f4)(0.f), a3 = (f4)(0.f);

        #pragma unroll
        for (int c = 0; c < CPG; ++c) {
            const f4 lv = *(const f4*)&Ls[c * 320 + hh * W_ + w0];
            const float* rp = &Rs[c * (H2 * RW) + hh * RW + (r0 - 4)];  // 16B-aligned
            const f4 ra = *(const f4*)(rp);
            const f4 rb = *(const f4*)(rp + 4);
            float rr[8];
            #pragma unroll
            for (int k = 0; k < 4; ++k) { rr[k] = ra[k]; rr[4 + k] = rb[k]; }
            // out(w0+i, d0+j) += L[w0+i] * R[r0 + i - j] -> rr[4 + i - j]
            #pragma unroll
            for (int j = 0; j < 4; ++j) {
                a0[j] += lv[0] * rr[4 + 0 - j];
                a1[j] += lv[1] * rr[4 + 1 - j];
                a2[j] += lv[2] * rr[4 + 2 - j];
                a3[j] += lv[3] * rr[4 + 3 - j];
            }
        }

        float* op = out + ((size_t)((n * G_ + g) * H_ + h0 + hh)) * (W_ * D_)
                    + (size_t)w0 * D_ + d0;
        *(f4*)(op + 0 * D_) = a0 * 0.125f;
        *(f4*)(op + 1 * D_) = a1 * 0.125f;
        *(f4*)(op + 2 * D_) = a2 * 0.125f;
        *(f4*)(op + 3 * D_) = a3 * 0.125f;
    }
}

extern "C" void kernel_launch(void* const* d_in, const int* in_sizes, int n_in,
                              void* d_out, int out_size, void* d_ws, size_t ws_size,
                              hipStream_t stream) {
    const float* Lg = (const float*)d_in[0];
    const float* Rg = (const float*)d_in[1];
    float* out = (float*)d_out;

    const int nblocks = N_ * G_ * (H_ / H2);   // 6400 blocks
    gw_cost_kernel<<<dim3(nblocks), dim3(512), 0, stream>>>(Lg, Rg, out);
}